// Round 2
// baseline (2421.377 us; speedup 1.0000x reference)
//
#include <hip/hip_runtime.h>

// ConvLSTM1D fused scan for MI355X — f32 I/O, bf16 MFMA.
// Round 8: halo ELIMINATED. One wave (64 thr) per block owns exactly 16
// j-rows; the single boundary row h[j0+16] needed by the recurrent conv is
// passed from the right-neighbor block through a static global ring
// (g_row[block][t][16 dwords], 50-step deep) with a release/acquire flag.
// Full-depth buffering => consumers may lag producers arbitrarily: no
// co-residency or lockstep needed (chain is one-directional; reversed tile
// mapping puts producers at LOWER blockIdx so they dispatch first; 2048
// one-wave blocks also fit resident at 8 blocks/CU).
// Wins vs round 6 (130us): 28% halo overcompute removed (VALU is the
// dominant pipe at 46%), per-step __syncthreads removed entirely (D->A
// transpose LDS round-trip is within-wave, lgkmcnt-ordered), 2048 fully
// independent chains fill the latency stalls that barriers used to expose.

#define TT   50
#define NBLK 2048          // 32 batches x 64 tiles
#define HSTR 40            // h row stride (shorts); mult of 8 -> 16B ds_read_b128
#define ROWS 17            // 16 owned + 1 halo row (row 16 stays 0; f0==15 patched)

typedef __attribute__((ext_vector_type(8))) short short8;
typedef __attribute__((ext_vector_type(4))) float floatx4;

// boundary-row ring: slot s in [1,49] holds h^s[j0] packed as 16 dwords
__device__ unsigned g_row[NBLK * TT * 16];
__device__ int g_flag[NBLK];

__device__ __forceinline__ unsigned short f2b_rne(float f) {
  union { float f; unsigned u; } v; v.f = f;
  unsigned r = v.u + 0x7FFFu + ((v.u >> 16) & 1u);
  return (unsigned short)(r >> 16);
}
__device__ __forceinline__ unsigned short f2b_trunc(float f) {
  union { float f; unsigned u; } v; v.f = f;
  return (unsigned short)(v.u >> 16);
}
__device__ __forceinline__ float hsig(float x) {
  return __builtin_amdgcn_fmed3f(__builtin_fmaf(0.2f, x, 0.5f), 0.0f, 1.0f);
}
__device__ __forceinline__ float ftanh(float x) {
  float e = __expf(2.0f * x);
  return 1.0f - 2.0f * __builtin_amdgcn_rcpf(e + 1.0f);
}

__global__ __launch_bounds__(64, 2)
void convlstm_scan(const float* __restrict__ xs,   // x [32][50][2048][8] f32
                   const float* __restrict__ ks,   // kernel [2][8][128] f32
                   const float* __restrict__ rks,  // rec_kernel [2][32][128] f32
                   const float* __restrict__ bs,   // bias [128] f32
                   const float* __restrict__ dws,  // dense_w [32768] f32
                   float* __restrict__ acc_out) {  // [32] f32 accumulators
  __shared__ short hbH[2][ROWS * HSTR];   // h (bf16), double-buffered

  const int hw   = blockIdx.x;
  const int b    = hw >> 6;
  const int rj   = hw & 63;          // reversed tile index: rj=0 <-> rightmost
  const int j0   = (63 - rj) * 16;   // logical j-range [j0, j0+16)
  const int lane = threadIdx.x;
  const int q    = lane >> 4;
  const int f0   = lane & 15;
  const bool consume = (rj != 0);    // has right neighbor = block hw-1
  const bool produce = (rj != 63);   // left neighbor (hw+1) consumes our row j0

  for (int e = lane; e < ROWS * HSTR; e += 64)   // 2 buffers x ROWS*HSTR shorts
    ((int*)hbH)[e] = 0;

  // ---- B fragments in registers, GATE-PAIR PERMUTED columns:
  // tile n = 2g+p, col f0 <-> oc = g*32 + 2*f0 + p; lane's two outputs per
  // row are adjacent h-cols 2f0, 2f0+1 (packed b32 LDS store).
  short8 Bwh0[8], Bwh1[8], Bxw[8];
#pragma unroll
  for (int n = 0; n < 8; ++n) {
    const int oc = (n >> 1) * 32 + 2 * f0 + (n & 1);
    short8 th;
#pragma unroll
    for (int j = 0; j < 8; ++j)
      th[j] = (short)f2b_rne(rks[(q * 8 + j) * 128 + oc]);
    Bwh0[n] = th;
#pragma unroll
    for (int j = 0; j < 8; ++j)
      th[j] = (short)f2b_rne(rks[(32 + q * 8 + j) * 128 + oc]);
    Bwh1[n] = th;
    // x-conv B: k rows 0..7 = tap0, 8..15 = tap1, row 16 = bias (ax carries
    // 1.0 there), rows 17..31 = 0.
    short8 tx = {0, 0, 0, 0, 0, 0, 0, 0};
    if (q < 2) {
#pragma unroll
      for (int j = 0; j < 8; ++j)
        tx[j] = (short)f2b_rne(ks[(q * 8 + j) * 128 + oc]);
    } else if (q == 2) {
      tx[0] = (short)f2b_rne(bs[oc]);
    }
    Bxw[n] = tx;
  }

  short8 axc = {0, 0, 0, 0, 0, 0, 0, 0};
  if (q == 2) axc[0] = (short)0x3F80;   // bias marker 1.0 at k=16
  const floatx4 zero4 = {0.0f, 0.0f, 0.0f, 0.0f};

  float cst[8];   // c-state, MFMA C-layout: [p*4 + r]
#pragma unroll
  for (int i = 0; i < 8; ++i) cst[i] = 0.0f;

  // ---- initial x prefetch (t=0); only q<2 lanes feed ax
  const float* xbase = xs + (size_t)b * TT * (2048 * 8);
  const int jm = j0 + f0;                 // <= 1023, no clamp needed
  floatx4 px0 = zero4, px1 = zero4;
  if (q < 2) {
    const float* xp = xbase + (size_t)(2 * jm + q) * 8;
    px0 = *(const floatx4*)xp;
    px1 = *(const floatx4*)(xp + 4);
  }

  float part = 0.0f;                      // fused Dense(1) partial

  for (int t = 0; t < TT; ++t) {
    const short* curH = hbH[t & 1];
    short* nxtH = hbH[(t & 1) ^ 1];
    const int last = (t == TT - 1);

    // 1) a-frag LDS reads (within-wave ordering; no barrier anywhere).
    short8 a0h = *(const short8*)&curH[f0 * HSTR + q * 8];
    short8 a1h = *(const short8*)&curH[(f0 + 1) * HSTR + q * 8];

    // 2) ax (x_hi) from registers prefetched last step.
    short8 ax = axc;
    if (q < 2) {
#pragma unroll
      for (int jj = 0; jj < 4; ++jj) ax[jj] = (short)f2b_trunc(px0[jj]);
#pragma unroll
      for (int jj = 0; jj < 4; ++jj) ax[4 + jj] = (short)f2b_trunc(px1[jj]);
    }

    // 3) next-step x prefetch (overlaps MFMA below).
    const int tn = last ? t : t + 1;
    if (q < 2) {
      const float* xp = xbase + ((size_t)tn * 2048 + (size_t)(2 * jm + q)) * 8;
      px0 = *(const floatx4*)xp;
      px1 = *(const floatx4*)(xp + 4);
    }

    // 4) MFMA groups 1+2 (independent of the neighbor row).
    floatx4 acc[8];
    __builtin_amdgcn_s_setprio(1);
#pragma unroll
    for (int n = 0; n < 8; ++n)
      acc[n] = __builtin_amdgcn_mfma_f32_16x16x32_bf16(ax, Bxw[n], zero4, 0, 0, 0);
#pragma unroll
    for (int n = 0; n < 8; ++n)
      acc[n] = __builtin_amdgcn_mfma_f32_16x16x32_bf16(a0h, Bwh0[n], acc[n], 0, 0, 0);
    __builtin_amdgcn_s_setprio(0);

    // 5) boundary row h^t[j0+16] from right neighbor (hw-1). Steady state:
    // flag already set -> no spin; 16 MFMAs above hide the poll latency.
    short8 halo = {0, 0, 0, 0, 0, 0, 0, 0};
    if (consume && t > 0) {
      while (__hip_atomic_load(&g_flag[hw - 1], __ATOMIC_RELAXED,
                               __HIP_MEMORY_SCOPE_AGENT) < t)
        __builtin_amdgcn_s_sleep(1);
      __builtin_amdgcn_fence(__ATOMIC_ACQUIRE, "agent");
      if (f0 == 15) {
        const unsigned* rp = &g_row[((hw - 1) * TT + t) * 16 + q * 4];
        union { unsigned u[4]; short8 s8; } cv;
#pragma unroll
        for (int i = 0; i < 4; ++i)
          cv.u[i] = __hip_atomic_load(rp + i, __ATOMIC_RELAXED,
                                      __HIP_MEMORY_SCOPE_AGENT);
        halo = cv.s8;
      }
    }
    if (f0 == 15) a1h = halo;   // rightmost block / t=0: stays zero (SAME pad)

    __builtin_amdgcn_s_setprio(1);
#pragma unroll
    for (int n = 0; n < 8; ++n)
      acc[n] = __builtin_amdgcn_mfma_f32_16x16x32_bf16(a1h, Bwh1[n], acc[n], 0, 0, 0);
    __builtin_amdgcn_s_setprio(0);

    // 6) Pointwise LSTM. D[row = q*4+r][tile n, col f0 -> h-col 2f0+(n&1)].
    const int jw = q * 4;
#pragma unroll
    for (int r = 0; r < 4; ++r) {
      float hv2[2];
#pragma unroll
      for (int p = 0; p < 2; ++p) {
        float zi = acc[0 + p][r], zf = acc[2 + p][r];
        float zc = acc[4 + p][r], zo = acc[6 + p][r];
        float ig = hsig(zi), fg = hsig(zf), og = hsig(zo);
        float cs = cst[p * 4 + r];
        float cn = __builtin_fmaf(fg, cs, ig * ftanh(zc));
        cst[p * 4 + r] = cn;
        hv2[p] = og * ftanh(cn);
      }
      if (!last) {
        unsigned pk = (unsigned)f2b_rne(hv2[0]) |
                      ((unsigned)f2b_rne(hv2[1]) << 16);
        *(unsigned*)&nxtH[(jw + r) * HSTR + 2 * f0] = pk;
        // publish row j0 (= row 0, held by q==0,r==0 lanes) for left neighbor
        if (produce && q == 0 && r == 0)
          __hip_atomic_store(&g_row[(hw * TT + t + 1) * 16 + f0], pk,
                             __ATOMIC_RELAXED, __HIP_MEMORY_SCOPE_AGENT);
      } else {
        // t=49: fused Dense(1); rows jw+r cover exactly [0,16).
        const int di = (j0 + jw + r) * 32 + 2 * f0;
        part = __builtin_fmaf(hv2[0], dws[di],
               __builtin_fmaf(hv2[1], dws[di + 1], part));
      }
    }
    if (!last && produce) {
      __builtin_amdgcn_fence(__ATOMIC_RELEASE, "agent");
      if (lane == 0)
        __hip_atomic_store(&g_flag[hw], t + 1, __ATOMIC_RELAXED,
                           __HIP_MEMORY_SCOPE_AGENT);
    }
  }

  // ---- reduce fused-dense partials (one atomic per block)
#pragma unroll
  for (int off = 32; off > 0; off >>= 1) part += __shfl_down(part, off);
  if (lane == 0) atomicAdd(&acc_out[b], part);
}

__global__ void init_acc(float* ws) {
  const int i = threadIdx.x;
  if (i < 32) ws[i] = 0.0f;
  for (int e = i; e < NBLK; e += 256) g_flag[e] = 0;
}

__global__ void finalize(const float* __restrict__ ws,
                         const float* __restrict__ db,
                         float* __restrict__ out) {
  int i = threadIdx.x;
  if (i < 32) out[i] = ws[i] + db[0];
}

extern "C" void kernel_launch(void* const* d_in, const int* in_sizes, int n_in,
                              void* d_out, int out_size, void* d_ws, size_t ws_size,
                              hipStream_t stream) {
  const float* x  = (const float*)d_in[0];
  const float* k  = (const float*)d_in[1];
  const float* rk = (const float*)d_in[2];
  const float* bi = (const float*)d_in[3];
  const float* dw = (const float*)d_in[4];
  const float* db = (const float*)d_in[5];
  float* ws = (float*)d_ws;
  float* out = (float*)d_out;

  hipLaunchKernelGGL(init_acc, dim3(1), dim3(256), 0, stream, ws);
  hipLaunchKernelGGL(convlstm_scan, dim3(NBLK), dim3(64), 0, stream,
                     x, k, rk, bi, dw, ws);
  hipLaunchKernelGGL(finalize, dim3(1), dim3(64), 0, stream, ws, db, out);
}

// Round 3
// 233.409 us; speedup vs baseline: 10.3739x; 10.3739x over previous
//
#include <hip/hip_runtime.h>

// ConvLSTM1D fused scan for MI355X — f32 I/O, bf16 MFMA.
// Round 9: revert to round-6 halo structure (round 8's cross-block handshake
// hit the non-coherent-XCD-L2 wall: ~20us/link agent-fence cost, 18x slower).
// Change vs round 6: B-fragments (rec_kernel / kernel / bias, gate-pair
// permuted, bf16) are PRECOMPUTED ONCE by a prep kernel into __device__
// tables laid out [n][lane] -> the scan kernel loads them with coalesced
// dwordx4 loads instead of re-running f2b_rne conversion chains, which the
// compiler was rematerializing INSIDE the 50-step loop (evidence: 24 short8
// frags = 96 VGPR of invariants can't fit in the reported VGPR_Count=104,
// and VALUBusy was ~2x the pointwise hand-count). Also: h-store pack now one
// v_cvt_pk_bf16_f32 (RNE, bit-identical) instead of 2x manual f2b_rne+or.
// Halo-tile trick: block owns j-range [j0, j0+64); recurrent conv reads h[j+1]
// only, so a right halo that starts at +49 rows and shrinks by 1 per step makes
// every block's 50-step scan fully independent (no grid sync).

#define TT 50
#define LTILE 64
#define ROWS 129   // 64 owned + 49 halo + 1 read-halo row (row 128 stays 0)
#define HSTR 40    // h row stride (shorts); mult of 8 -> 16B-aligned ds_read_b128

typedef __attribute__((ext_vector_type(8))) short short8;
typedef __attribute__((ext_vector_type(4))) float floatx4;

// Prepermuted bf16 weight fragment tables: index [n*64 + lane].
__device__ short8 g_tw0[512];   // rec_kernel tap rows 0..31  (k = q*8+j)
__device__ short8 g_tw1[512];   // rec_kernel tap rows 32..63
__device__ short8 g_txw[512];   // x-conv taps (k rows 0..15) + bias row 16

__device__ __forceinline__ unsigned short f2b_rne(float f) {
  union { float f; unsigned u; } v; v.f = f;
  unsigned r = v.u + 0x7FFFu + ((v.u >> 16) & 1u);
  return (unsigned short)(r >> 16);
}
__device__ __forceinline__ unsigned short f2b_trunc(float f) {
  union { float f; unsigned u; } v; v.f = f;
  return (unsigned short)(v.u >> 16);
}
__device__ __forceinline__ float hsig(float x) {
  return __builtin_amdgcn_fmed3f(__builtin_fmaf(0.2f, x, 0.5f), 0.0f, 1.0f);
}
__device__ __forceinline__ float ftanh(float x) {
  float e = __expf(2.0f * x);
  return 1.0f - 2.0f * __builtin_amdgcn_rcpf(e + 1.0f);
}

// ---- prep: build fragment tables (once) + zero the batch accumulators.
__global__ void prep(const float* __restrict__ ks,
                     const float* __restrict__ rks,
                     const float* __restrict__ bs,
                     float* __restrict__ ws) {
  const int lane = threadIdx.x;        // 0..63
  if (lane < 32) ws[lane] = 0.0f;
  const int q  = lane >> 4;
  const int f0 = lane & 15;
#pragma unroll
  for (int n = 0; n < 8; ++n) {
    // Gate-pair permutation: tile n = 2g+p, col f0  <->  oc = g*32 + 2*f0 + p
    const int oc = (n >> 1) * 32 + 2 * f0 + (n & 1);
    short8 th;
#pragma unroll
    for (int j = 0; j < 8; ++j)
      th[j] = (short)f2b_rne(rks[(q * 8 + j) * 128 + oc]);
    g_tw0[n * 64 + lane] = th;
#pragma unroll
    for (int j = 0; j < 8; ++j)
      th[j] = (short)f2b_rne(rks[(32 + q * 8 + j) * 128 + oc]);
    g_tw1[n * 64 + lane] = th;
    // x-conv B: k rows 0..7 = tap0, 8..15 = tap1 (paired with x_hi),
    // row 16 = bias (ax carries 1.0 there), rows 17..31 = 0.
    short8 tx = {0, 0, 0, 0, 0, 0, 0, 0};
    if (q < 2) {
#pragma unroll
      for (int j = 0; j < 8; ++j)
        tx[j] = (short)f2b_rne(ks[(q * 8 + j) * 128 + oc]);
    } else if (q == 2) {
      tx[0] = (short)f2b_rne(bs[oc]);
    }
    g_txw[n * 64 + lane] = tx;
  }
}

__global__ __launch_bounds__(256, 2)
void convlstm_scan(const float* __restrict__ xs,   // x [32][50][2048][8] f32
                   const float* __restrict__ dws,  // dense_w [32768] f32
                   float* __restrict__ acc_out) {  // [32] f32 accumulators
  __shared__ short hbH[2][ROWS * HSTR];   // h (bf16), double-buffered

  const int tid  = threadIdx.x;
  const int b    = blockIdx.x >> 4;
  const int j0   = (blockIdx.x & 15) * LTILE;
  const int wave = tid >> 6;
  const int lane = tid & 63;
  const int q    = lane >> 4;
  const int f0   = lane & 15;

  for (int e = tid; e < ROWS * HSTR; e += 256)
    ((int*)hbH)[e] = 0;

  // ---- B fragments: coalesced loads from the prepermuted tables.
  // tile n = 2g+p, col f0  <->  oc = g*32 + 2*f0 + p  => lane f0's two
  // outputs per row are adjacent h-cols 2f0, 2f0+1 (packed b32 store).
  short8 Bwh0[8], Bwh1[8], Bxw[8];
#pragma unroll
  for (int n = 0; n < 8; ++n) {
    Bwh0[n] = g_tw0[n * 64 + lane];
    Bwh1[n] = g_tw1[n * 64 + lane];
    Bxw[n]  = g_txw[n * 64 + lane];
  }

  // ax constant part: lane (q=2, elem 0) = bf16 1.0 (bias marker), else 0.
  short8 axc = {0, 0, 0, 0, 0, 0, 0, 0};
  if (q == 2) axc[0] = (short)0x3F80;

  const floatx4 zero4 = {0.0f, 0.0f, 0.0f, 0.0f};

  float cst[2][8];   // c-state, MFMA C-layout: [m-slot][p*4 + r]
#pragma unroll
  for (int s = 0; s < 2; ++s)
#pragma unroll
    for (int i = 0; i < 8; ++i) cst[s][i] = 0.0f;

  // ---- initial x prefetch (t=0) for both slots
  floatx4 px0[2], px1[2];
#pragma unroll
  for (int s = 0; s < 2; ++s) {
    const int jr = (wave + 4 * s) * 16 + f0;
    const int jm = min(j0 + jr, 1023);
    const float* xp = xs + (size_t)b * TT * (2048 * 8) +
                      (size_t)(2 * jm + (q & 1)) * 8;
    px0[s] = *(const floatx4*)xp;
    px1[s] = *(const floatx4*)(xp + 4);
  }

  const int maxrows = 1024 - j0;
  float part = 0.0f;                        // fused Dense(1) partial
  __syncthreads();

  for (int t = 0; t < TT; ++t) {
    const short* curH = hbH[t & 1];
    short* nxtH = hbH[(t & 1) ^ 1];
    int rows = LTILE + (TT - 1) - t;          // halo shrinks 1/step
    if (rows > maxrows) rows = maxrows;
    const int nmt = (rows + 15) >> 4;         // 4..8; slot0 (m=wave) always live
    const int act1 = (wave + 4) < nmt;        // wave-uniform slot1 guard
    const int last = (t == TT - 1);
    const int tn = last ? t : t + 1;
    const float* xnext = xs + ((size_t)(b * TT + tn)) * (2048 * 8);

    // 1) Front-load a-frag LDS reads (both slots; max row read = 128 = ROWS-1).
    short8 a0h[2], a1h[2];
#pragma unroll
    for (int s = 0; s < 2; ++s) {
      const int jr = (wave + 4 * s) * 16 + f0;
      a0h[s] = *(const short8*)&curH[jr * HSTR + q * 8];
      a1h[s] = *(const short8*)&curH[(jr + 1) * HSTR + q * 8];
    }

    // 2) Build ax (x_hi) from registers prefetched last step.
    // k = q*8+j: q0 -> hi(x[2J][j]), q1 -> hi(x[2J+1][j]), q2 -> bias marker.
    short8 ax[2];
#pragma unroll
    for (int s = 0; s < 2; ++s) {
      ax[s] = axc;
      if (q < 2) {
        floatx4 x0 = px0[s], x1 = px1[s];
#pragma unroll
        for (int jj = 0; jj < 4; ++jj) ax[s][jj] = (short)f2b_trunc(x0[jj]);
#pragma unroll
        for (int jj = 0; jj < 4; ++jj) ax[s][4 + jj] = (short)f2b_trunc(x1[jj]);
      }
    }

    // 3) Issue next-step x prefetch (longest latency, overlaps MFMA below).
#pragma unroll
    for (int s = 0; s < 2; ++s) {
      const int jr = (wave + 4 * s) * 16 + f0;
      const int jm = min(j0 + jr, 1023);
      const float* xp = xnext + (size_t)(2 * jm + (q & 1)) * 8;
      px0[s] = *(const floatx4*)xp;
      px1[s] = *(const floatx4*)(xp + 4);
    }

    // 4) Per-slot MFMA + pointwise.
#pragma unroll
    for (int s = 0; s < 2; ++s) {
      if (s == 1 && !act1) continue;
      const int m = wave + 4 * s;

      floatx4 acc[8];
      // ax first: operands in registers, C = zero4; issues while ds_reads land.
#pragma unroll
      for (int n = 0; n < 8; ++n)
        acc[n] = __builtin_amdgcn_mfma_f32_16x16x32_bf16(ax[s], Bxw[n], zero4, 0, 0, 0);
#pragma unroll
      for (int n = 0; n < 8; ++n)
        acc[n] = __builtin_amdgcn_mfma_f32_16x16x32_bf16(a0h[s], Bwh0[n], acc[n], 0, 0, 0);
#pragma unroll
      for (int n = 0; n < 8; ++n)
        acc[n] = __builtin_amdgcn_mfma_f32_16x16x32_bf16(a1h[s], Bwh1[n], acc[n], 0, 0, 0);

      // Pointwise LSTM. D[m-row = q*4+r][tile n, col f0 -> h-col 2f0 + (n&1)].
      // Gate g in tiles {2g, 2g+1}: zi=acc[0+p], zf=acc[2+p], zc=acc[4+p],
      // zo=acc[6+p] give h-col 2f0+p.
      const int jw = m * 16 + q * 4;
#pragma unroll
      for (int r = 0; r < 4; ++r) {
        float hv2[2];
#pragma unroll
        for (int p = 0; p < 2; ++p) {
          float zi = acc[0 + p][r], zf = acc[2 + p][r];
          float zc = acc[4 + p][r], zo = acc[6 + p][r];
          float ig = hsig(zi), fg = hsig(zf), og = hsig(zo);
          float cs = cst[s][p * 4 + r];
          float cn = __builtin_fmaf(fg, cs, ig * ftanh(zc));
          cst[s][p * 4 + r] = cn;
          hv2[p] = og * ftanh(cn);
        }
        if (!last) {
          unsigned pk;
          asm("v_cvt_pk_bf16_f32 %0, %1, %2"
              : "=v"(pk) : "v"(hv2[0]), "v"(hv2[1]));
          *(unsigned*)&nxtH[(jw + r) * HSTR + 2 * f0] = pk;
        } else {
          // t=49: nmt=4, s=0 only; rows jw+r cover exactly [0,64).
          const int di = (j0 + jw + r) * 32 + 2 * f0;
          part = __builtin_fmaf(hv2[0], dws[di],
                 __builtin_fmaf(hv2[1], dws[di + 1], part));
        }
      }
    }
    __syncthreads();
  }

  // ---- reduce fused-dense partials
#pragma unroll
  for (int off = 32; off > 0; off >>= 1) part += __shfl_down(part, off);
  if (lane == 0) atomicAdd(&acc_out[b], part);
}

__global__ void finalize(const float* __restrict__ ws,
                         const float* __restrict__ db,
                         float* __restrict__ out) {
  int i = threadIdx.x;
  if (i < 32) out[i] = ws[i] + db[0];
}

extern "C" void kernel_launch(void* const* d_in, const int* in_sizes, int n_in,
                              void* d_out, int out_size, void* d_ws, size_t ws_size,
                              hipStream_t stream) {
  const float* x  = (const float*)d_in[0];
  const float* k  = (const float*)d_in[1];
  const float* rk = (const float*)d_in[2];
  const float* bi = (const float*)d_in[3];
  const float* dw = (const float*)d_in[4];
  const float* db = (const float*)d_in[5];
  float* ws = (float*)d_ws;
  float* out = (float*)d_out;

  hipLaunchKernelGGL(prep, dim3(1), dim3(64), 0, stream, k, rk, bi, ws);
  hipLaunchKernelGGL(convlstm_scan, dim3(512), dim3(256), 0, stream,
                     x, dw, ws);
  hipLaunchKernelGGL(finalize, dim3(1), dim3(64), 0, stream, ws, db, out);
}